// Round 1
// baseline (1122.254 us; speedup 1.0000x reference)
//
#include <hip/hip_runtime.h>
#include <math.h>

#define NN 50000
#define NE 800000
#define IC 256
#define EPS 1e-5f

// ---------------- ws layout (float offsets) ----------------
enum : int {
  OFF_SCALE  = 0,                       // [256]
  OFF_SHIFT  = 256,                     // [256]
  OFF_S1     = 512,                     // [256]  zeroed
  OFF_S2     = 768,                     // [256]  zeroed
  OFF_MENC   = 1024,                    // [NN*4] unsigned, zeroed
  OFF_DENOM  = OFF_MENC + 200000,       // [NN*4] zeroed
  OFF_COUNTS = OFF_DENOM + 200000,      // [NN] int, zeroed
  OFF_CURSOR = OFF_COUNTS + 50000,      // [NN] int, zeroed (overwritten by scan)
  ZERO_END   = OFF_CURSOR + 50000,
  OFF_START  = ZERO_END,                // [NN+1] int
  OFF_ALS    = OFF_START + 50004,       // [NN*4]
  OFF_ALD    = OFF_ALS + 200000,        // [NN*4]
  OFF_SRT    = OFF_ALD + 200000,        // int2 [NE] -> 1600000 ints
  OFF_W      = OFF_SRT + 1600000,       // [NE*4] float; reused as e3[NE] in layer 2
  OFF_YLIN   = OFF_W + 3200000,         // [NN*256]; becomes x1 in-place
  OFF_H      = OFF_YLIN + 12800000,     // [NN*256]
  OFF_Y3     = OFF_H + 12800000,        // [NN*2]
  OFF_H3     = OFF_Y3 + 100000,         // [NN*2]
  OFF_AL3S   = OFF_H3 + 100000,         // [NN]
  OFF_AL3D   = OFF_AL3S + 50000,        // [NN]
  WS_FLOATS  = OFF_AL3D + 50000         // ~126.6 MB
};

__device__ __forceinline__ float lrelu(float s) { return s > 0.f ? s : 0.2f * s; }
// order-preserving float->uint encoding for atomicMax
__device__ __forceinline__ unsigned fenc(float f) {
  unsigned u = __float_as_uint(f);
  return (u & 0x80000000u) ? ~u : (u | 0x80000000u);
}
__device__ __forceinline__ float fdec(unsigned u) {
  return __uint_as_float((u & 0x80000000u) ? (u & 0x7fffffffu) : ~u);
}

// ---------------- BN stats: per-column sum / sumsq ----------------
__global__ __launch_bounds__(256) void k_bnstats(const float* __restrict__ x,
                                                 float* __restrict__ S1,
                                                 float* __restrict__ S2) {
  int c = threadIdx.x;
  float s1 = 0.f, s2 = 0.f;
  for (int r = blockIdx.x; r < NN; r += gridDim.x) {
    float v = x[r * IC + c];
    s1 += v;
    s2 = fmaf(v, v, s2);
  }
  atomicAdd(&S1[c], s1);
  atomicAdd(&S2[c], s2);
}

__global__ __launch_bounds__(256) void k_bnfin(const float* __restrict__ S1,
                                               const float* __restrict__ S2,
                                               const float* __restrict__ g,
                                               const float* __restrict__ b,
                                               float* __restrict__ scale,
                                               float* __restrict__ shift) {
  int c = threadIdx.x;
  float mu = S1[c] * (1.f / NN);
  float var = S2[c] * (1.f / NN) - mu * mu;
  float s = g[c] / sqrtf(var + EPS);
  scale[c] = s;
  shift[c] = b[c] - mu * s;
}

// ---------------- fused dual GEMM: [ylin | h] = bn(x) @ [Wlin | Wcon] ----------------
__global__ __launch_bounds__(256) void k_gemm1(const float* __restrict__ x,
                                               const float* __restrict__ scale,
                                               const float* __restrict__ shift,
                                               const float* __restrict__ Wlin,
                                               const float* __restrict__ Wcon,
                                               float* __restrict__ ylin,
                                               float* __restrict__ h) {
  __shared__ float As[32][68];  // [k][m], stride 68 keeps 16B alignment
  __shared__ float Bs[32][68];  // [k][n]
  const int tid = threadIdx.x;
  const int bm = blockIdx.x, bn = blockIdx.y;
  const float* __restrict__ B = ((bn < 4) ? Wlin : Wcon) + (bn & 3) * 64;
  float* __restrict__ out = (bn < 4) ? ylin : h;
  const int row0 = bm * 64;
  const int tm = tid >> 4, tn = tid & 15;
  const int lax = tid & 31, lay = tid >> 5;
  const int lbx = tid & 63, lby = tid >> 6;
  float acc[4][4] = {};
  for (int k0 = 0; k0 < IC; k0 += 32) {
#pragma unroll
    for (int i = 0; i < 8; ++i) {
      int r = row0 + lay + i * 8;
      int c = k0 + lax;
      float v = (r < NN) ? x[r * IC + c] : 0.f;
      As[lax][lay + i * 8] = fmaf(v, scale[c], shift[c]);
    }
#pragma unroll
    for (int i = 0; i < 8; ++i) {
      int c = k0 + lby + i * 4;
      Bs[lby + i * 4][lbx] = B[c * IC + lbx];
    }
    __syncthreads();
#pragma unroll
    for (int k = 0; k < 32; ++k) {
      float4 av = *(const float4*)&As[k][tm * 4];
      float4 bv = *(const float4*)&Bs[k][tn * 4];
      float a[4] = {av.x, av.y, av.z, av.w};
      float bb[4] = {bv.x, bv.y, bv.z, bv.w};
#pragma unroll
      for (int i = 0; i < 4; ++i)
#pragma unroll
        for (int j = 0; j < 4; ++j) acc[i][j] = fmaf(a[i], bb[j], acc[i][j]);
    }
    __syncthreads();
  }
#pragma unroll
  for (int i = 0; i < 4; ++i) {
    int r = row0 + tm * 4 + i;
    if (r < NN) {
      float4 v = make_float4(acc[i][0], acc[i][1], acc[i][2], acc[i][3]);
      *(float4*)&out[r * IC + (bn & 3) * 64 + tn * 4] = v;
    }
  }
}

// ---------------- attention logits: als/ald[n,h] = sum_c h[n,h,c]*a[h,c] ----------------
__global__ __launch_bounds__(256) void k_alpha(const float4* __restrict__ h4,
                                               const float4* __restrict__ as4,
                                               const float4* __restrict__ ad4,
                                               float* __restrict__ als,
                                               float* __restrict__ ald) {
  int n = (blockIdx.x * 256 + threadIdx.x) >> 6;
  int lane = threadIdx.x & 63;
  float4 hv = h4[n * 64 + lane];
  float4 a = as4[lane], d = ad4[lane];
  float ps = hv.x * a.x + hv.y * a.y + hv.z * a.z + hv.w * a.w;
  float pd = hv.x * d.x + hv.y * d.y + hv.z * d.z + hv.w * d.w;
#pragma unroll
  for (int off = 1; off < 16; off <<= 1) {
    ps += __shfl_xor(ps, off, 64);
    pd += __shfl_xor(pd, off, 64);
  }
  if ((lane & 15) == 0) {
    als[n * 4 + (lane >> 4)] = ps;
    ald[n * 4 + (lane >> 4)] = pd;
  }
}

// ---------------- counting sort by dst ----------------
__global__ __launch_bounds__(256) void k_hist(const int* __restrict__ dst,
                                              int* __restrict__ counts) {
  int e = blockIdx.x * 256 + threadIdx.x;
  atomicAdd(&counts[dst[e]], 1);
}

__global__ __launch_bounds__(1024) void k_scan(const int* __restrict__ counts,
                                               int* __restrict__ start,
                                               int* __restrict__ cursor) {
  __shared__ int buf[1024];
  __shared__ int carry;
  int tid = threadIdx.x;
  if (tid == 0) carry = 0;
  __syncthreads();
  for (int base = 0; base < NN; base += 1024) {
    int i = base + tid;
    int v = (i < NN) ? counts[i] : 0;
    buf[tid] = v;
    __syncthreads();
    for (int off = 1; off < 1024; off <<= 1) {
      int t = (tid >= off) ? buf[tid - off] : 0;
      __syncthreads();
      buf[tid] += t;
      __syncthreads();
    }
    int excl = carry + buf[tid] - v;
    if (i < NN) {
      start[i] = excl;
      cursor[i] = excl;
    }
    __syncthreads();
    if (tid == 0) carry += buf[1023];
    __syncthreads();
  }
  if (tid == 0) start[NN] = carry;
}

__global__ __launch_bounds__(256) void k_scatter(const int* __restrict__ src,
                                                 const int* __restrict__ dst,
                                                 int* __restrict__ cursor,
                                                 int2* __restrict__ srt) {
  int e = blockIdx.x * 256 + threadIdx.x;
  int d = dst[e];
  int pos = atomicAdd(&cursor[d], 1);
  srt[pos] = make_int2(src[e], e);
}

// ---------------- edge passes: segment max, then exp + denom ----------------
__global__ __launch_bounds__(256) void k_edgemax(const int* __restrict__ src,
                                                 const int* __restrict__ dst,
                                                 const float4* __restrict__ als4,
                                                 const float4* __restrict__ ald4,
                                                 unsigned* __restrict__ menc) {
  int e = blockIdx.x * 256 + threadIdx.x;
  int s = src[e], d = dst[e];
  float4 a = als4[s], b = ald4[d];
  atomicMax(&menc[d * 4 + 0], fenc(lrelu(a.x + b.x)));
  atomicMax(&menc[d * 4 + 1], fenc(lrelu(a.y + b.y)));
  atomicMax(&menc[d * 4 + 2], fenc(lrelu(a.z + b.z)));
  atomicMax(&menc[d * 4 + 3], fenc(lrelu(a.w + b.w)));
}

__global__ __launch_bounds__(256) void k_edgeexp(const int* __restrict__ src,
                                                 const int* __restrict__ dst,
                                                 const float4* __restrict__ als4,
                                                 const float4* __restrict__ ald4,
                                                 const uint4* __restrict__ menc4,
                                                 float* __restrict__ denom,
                                                 float4* __restrict__ w4) {
  int e = blockIdx.x * 256 + threadIdx.x;
  int s = src[e], d = dst[e];
  float4 a = als4[s], b = ald4[d];
  uint4 m = menc4[d];
  float4 wv;
  wv.x = expf(lrelu(a.x + b.x) - fdec(m.x));
  wv.y = expf(lrelu(a.y + b.y) - fdec(m.y));
  wv.z = expf(lrelu(a.z + b.z) - fdec(m.z));
  wv.w = expf(lrelu(a.w + b.w) - fdec(m.w));
  atomicAdd(&denom[d * 4 + 0], wv.x);
  atomicAdd(&denom[d * 4 + 1], wv.y);
  atomicAdd(&denom[d * 4 + 2], wv.z);
  atomicAdd(&denom[d * 4 + 3], wv.w);
  w4[e] = wv;
}

// ---------------- aggregation: wave per dst; fused epilogue -> x1 (in place of ylin) ----
__global__ __launch_bounds__(256) void k_agg1(const float4* __restrict__ h4,
                                              float4* __restrict__ ylin4,
                                              const float* __restrict__ w,
                                              const float* __restrict__ denom,
                                              const int* __restrict__ start,
                                              const int2* __restrict__ srt,
                                              const float4* __restrict__ b1,
                                              const float4* __restrict__ b2) {
  int n = (blockIdx.x * 256 + threadIdx.x) >> 6;
  int lane = threadIdx.x & 63;
  int head = lane >> 4;
  int s = start[n], t = start[n + 1];
  float4 acc = make_float4(0.f, 0.f, 0.f, 0.f);
  for (int i = s; i < t; ++i) {
    int2 se = srt[i];
    float wv = w[se.y * 4 + head];
    float4 hv = h4[se.x * 64 + lane];
    acc.x = fmaf(wv, hv.x, acc.x);
    acc.y = fmaf(wv, hv.y, acc.y);
    acc.z = fmaf(wv, hv.z, acc.z);
    acc.w = fmaf(wv, hv.w, acc.w);
  }
  float inv = 1.f / (denom[n * 4 + head] + 1e-16f);
  float4 yl = ylin4[n * 64 + lane];
  float4 bb1 = b1[lane], bb2 = b2[lane];
  float4 r;
  r.x = fmaxf(fmaf(acc.x, inv, yl.x + bb1.x + bb2.x), 0.f);
  r.y = fmaxf(fmaf(acc.y, inv, yl.y + bb1.y + bb2.y), 0.f);
  r.z = fmaxf(fmaf(acc.z, inv, yl.z + bb1.z + bb2.z), 0.f);
  r.w = fmaxf(fmaf(acc.w, inv, yl.w + bb1.w + bb2.w), 0.f);
  ylin4[n * 64 + lane] = r;
}

// ---------------- layer 2 node kernel: BN + lin3 + con3 + logits ----------------
__global__ __launch_bounds__(256) void k_node2(const float4* __restrict__ x14,
                                               const float4* __restrict__ scale4,
                                               const float4* __restrict__ shift4,
                                               const float4* __restrict__ Wl4,
                                               const float4* __restrict__ Wc4,
                                               const float* __restrict__ a3s,
                                               const float* __restrict__ a3d,
                                               float* __restrict__ y3,
                                               float* __restrict__ h3,
                                               float* __restrict__ al3s,
                                               float* __restrict__ al3d) {
  int n = (blockIdx.x * 256 + threadIdx.x) >> 6;
  int lane = threadIdx.x & 63;
  float4 xv = x14[n * 64 + lane];
  float4 sc = scale4[lane], sh = shift4[lane];
  float x0 = fmaf(xv.x, sc.x, sh.x);
  float x1 = fmaf(xv.y, sc.y, sh.y);
  float x2 = fmaf(xv.z, sc.z, sh.z);
  float x3 = fmaf(xv.w, sc.w, sh.w);
  float4 wa = Wl4[lane * 2], wb = Wl4[lane * 2 + 1];
  float y0 = x0 * wa.x + x1 * wa.z + x2 * wb.x + x3 * wb.z;
  float y1 = x0 * wa.y + x1 * wa.w + x2 * wb.y + x3 * wb.w;
  float4 ca = Wc4[lane * 2], cb = Wc4[lane * 2 + 1];
  float g0 = x0 * ca.x + x1 * ca.z + x2 * cb.x + x3 * cb.z;
  float g1 = x0 * ca.y + x1 * ca.w + x2 * cb.y + x3 * cb.w;
#pragma unroll
  for (int off = 1; off < 64; off <<= 1) {
    y0 += __shfl_xor(y0, off, 64);
    y1 += __shfl_xor(y1, off, 64);
    g0 += __shfl_xor(g0, off, 64);
    g1 += __shfl_xor(g1, off, 64);
  }
  if (lane == 0) {
    y3[2 * n] = y0;
    y3[2 * n + 1] = y1;
    h3[2 * n] = g0;
    h3[2 * n + 1] = g1;
    al3s[n] = g0 * a3s[0] + g1 * a3s[1];
    al3d[n] = g0 * a3d[0] + g1 * a3d[1];
  }
}

__global__ __launch_bounds__(256) void k_edge2(const int* __restrict__ src,
                                               const int* __restrict__ dst,
                                               const float* __restrict__ al3s,
                                               const float* __restrict__ al3d,
                                               float* __restrict__ e3) {
  int e = blockIdx.x * 256 + threadIdx.x;
  e3[e] = lrelu(al3s[src[e]] + al3d[dst[e]]);
}

// ---------------- layer 2 softmax-aggregate + final output ----------------
__global__ __launch_bounds__(256) void k_final(const int* __restrict__ start,
                                               const int2* __restrict__ srt,
                                               const float* __restrict__ e3,
                                               const float2* __restrict__ h32,
                                               const float* __restrict__ y3,
                                               const float* __restrict__ l3b,
                                               const float* __restrict__ c3b,
                                               float* __restrict__ out) {
  int n = blockIdx.x * 256 + threadIdx.x;
  if (n >= NN) return;
  int s = start[n], t = start[n + 1];
  float m = -INFINITY;
  for (int i = s; i < t; ++i) m = fmaxf(m, e3[srt[i].y]);
  float den = 0.f, a0 = 0.f, a1 = 0.f;
  for (int i = s; i < t; ++i) {
    int2 se = srt[i];
    float wv = expf(e3[se.y] - m);
    den += wv;
    float2 hv = h32[se.x];
    a0 = fmaf(wv, hv.x, a0);
    a1 = fmaf(wv, hv.y, a1);
  }
  float inv = 1.f / (den + 1e-16f);
  out[2 * n] = fmaxf(y3[2 * n] + l3b[0] + c3b[0] + a0 * inv, 0.f);
  out[2 * n + 1] = fmaxf(y3[2 * n + 1] + l3b[1] + c3b[1] + a1 * inv, 0.f);
}

extern "C" void kernel_launch(void* const* d_in, const int* in_sizes, int n_in,
                              void* d_out, int out_size, void* d_ws, size_t ws_size,
                              hipStream_t stream) {
  const float* x = (const float*)d_in[0];
  const int* ei = (const int*)d_in[1];
  const float* bn1_g = (const float*)d_in[2];
  const float* bn1_b = (const float*)d_in[3];
  const float* lin1_W = (const float*)d_in[4];
  const float* lin1_b = (const float*)d_in[5];
  const float* con1_W = (const float*)d_in[6];
  const float* con1_as = (const float*)d_in[7];
  const float* con1_ad = (const float*)d_in[8];
  const float* con1_b = (const float*)d_in[9];
  const float* bn3_g = (const float*)d_in[10];
  const float* bn3_b = (const float*)d_in[11];
  const float* lin3_W = (const float*)d_in[12];
  const float* lin3_b = (const float*)d_in[13];
  const float* con3_W = (const float*)d_in[14];
  const float* con3_as = (const float*)d_in[15];
  const float* con3_ad = (const float*)d_in[16];
  const float* con3_b = (const float*)d_in[17];
  float* ws = (float*)d_ws;
  const int* srcA = ei;
  const int* dstA = ei + NE;

  float* scale = ws + OFF_SCALE;
  float* shift = ws + OFF_SHIFT;
  float* S1 = ws + OFF_S1;
  float* S2 = ws + OFF_S2;
  unsigned* menc = (unsigned*)(ws + OFF_MENC);
  float* denom = ws + OFF_DENOM;
  int* counts = (int*)(ws + OFF_COUNTS);
  int* cursor = (int*)(ws + OFF_CURSOR);
  int* start = (int*)(ws + OFF_START);
  float* als = ws + OFF_ALS;
  float* ald = ws + OFF_ALD;
  int2* srt = (int2*)(ws + OFF_SRT);
  float* w = ws + OFF_W;     // layer1 exp weights; reused as e3 in layer 2
  float* ylin = ws + OFF_YLIN;  // becomes x1 in place
  float* h = ws + OFF_H;
  float* y3 = ws + OFF_Y3;
  float* h3 = ws + OFF_H3;
  float* al3s = ws + OFF_AL3S;
  float* al3d = ws + OFF_AL3D;

  // zero: S1,S2,menc,denom,counts,cursor (contiguous)
  hipMemsetAsync(ws + OFF_S1, 0, (size_t)(ZERO_END - OFF_S1) * sizeof(float), stream);

  // ---- layer 1 ----
  k_bnstats<<<256, 256, 0, stream>>>(x, S1, S2);
  k_bnfin<<<1, 256, 0, stream>>>(S1, S2, bn1_g, bn1_b, scale, shift);
  k_gemm1<<<dim3(782, 8), 256, 0, stream>>>(x, scale, shift, lin1_W, con1_W, ylin, h);
  k_alpha<<<12500, 256, 0, stream>>>((const float4*)h, (const float4*)con1_as,
                                     (const float4*)con1_ad, als, ald);
  k_hist<<<3125, 256, 0, stream>>>(dstA, counts);
  k_scan<<<1, 1024, 0, stream>>>(counts, start, cursor);
  k_scatter<<<3125, 256, 0, stream>>>(srcA, dstA, cursor, srt);
  k_edgemax<<<3125, 256, 0, stream>>>(srcA, dstA, (const float4*)als,
                                      (const float4*)ald, menc);
  k_edgeexp<<<3125, 256, 0, stream>>>(srcA, dstA, (const float4*)als,
                                      (const float4*)ald, (const uint4*)menc, denom,
                                      (float4*)w);
  k_agg1<<<12500, 256, 0, stream>>>((const float4*)h, (float4*)ylin, w, denom, start,
                                    srt, (const float4*)lin1_b, (const float4*)con1_b);

  // ---- layer 2 ----
  hipMemsetAsync(ws + OFF_S1, 0, 512 * sizeof(float), stream);
  k_bnstats<<<256, 256, 0, stream>>>(ylin, S1, S2);
  k_bnfin<<<1, 256, 0, stream>>>(S1, S2, bn3_g, bn3_b, scale, shift);
  k_node2<<<12500, 256, 0, stream>>>((const float4*)ylin, (const float4*)scale,
                                     (const float4*)shift, (const float4*)lin3_W,
                                     (const float4*)con3_W, con3_as, con3_ad, y3, h3,
                                     al3s, al3d);
  k_edge2<<<3125, 256, 0, stream>>>(srcA, dstA, al3s, al3d, w);
  k_final<<<196, 256, 0, stream>>>(start, srt, w, (const float2*)h3, y3, lin3_b,
                                   con3_b, (float*)d_out);
}

// Round 2
// 552.135 us; speedup vs baseline: 2.0326x; 2.0326x over previous
//
#include <hip/hip_runtime.h>
#include <math.h>

#define NN 50000
#define NE 800000
#define IC 256
#define EPS 1e-5f

typedef __attribute__((ext_vector_type(8))) short short8;   // 8 bf16 (4 VGPRs)
typedef __attribute__((ext_vector_type(4))) float f32x4;    // MFMA acc

// ---------------- ws layout (float offsets) ----------------
enum : int {
  OFF_SCALE  = 0,                        // [256]
  OFF_SHIFT  = 256,                      // [256]
  OFF_S1     = 512,                      // [256] zeroed
  OFF_S2     = 768,                      // [256] zeroed
  OFF_COUNTS = 1024,                     // int[NN] zeroed
  ZERO_END   = OFF_COUNTS + 50000,
  OFF_CURSOR = ZERO_END,                 // int[NN]
  OFF_START  = OFF_CURSOR + 50000,       // int[NN+1] (pad 50004)
  OFF_BSUM   = OFF_START + 50004,        // int[64]
  OFF_BOFF   = OFF_BSUM + 64,            // int[64]
  OFF_ALS    = OFF_BOFF + 64,            // [NN*4]  (16B aligned: 151156%4==0)
  OFF_ALD    = OFF_ALS + 200000,         // [NN*4]
  OFF_SRCS   = OFF_ALD + 200000,         // int[NE]
  OFF_Y3     = OFF_SRCS + 800000,        // [NN*2]
  OFF_H3     = OFF_Y3 + 100000,          // [NN*2]
  OFF_AL3S   = OFF_H3 + 100000,          // [NN]
  OFF_AL3D   = OFF_AL3S + 50000,         // [NN]
  OFF_BFH    = OFF_AL3D + 50000,         // ushort[131072] = 65536 floats
  OFF_BFL    = OFF_BFH + 65536,          // ushort[131072]
  OFF_HBF    = OFF_BFL + 65536,          // ushort[NN*256] = 6.4M floats (16B aligned)
  OFF_YLIN   = OFF_HBF + 6400000,        // [NN*256] fp32; becomes x1 in-place
  WS_FLOATS  = OFF_YLIN + 12800000       // ~84 MB
};

__device__ __forceinline__ float lrelu(float s) { return s > 0.f ? s : 0.2f * s; }
__device__ __forceinline__ float b2f(unsigned short u) {
  return __uint_as_float(((unsigned)u) << 16);
}
__device__ __forceinline__ unsigned short f2bf(float f) {  // RNE
  unsigned u = __float_as_uint(f);
  return (unsigned short)((u + 0x7fffu + ((u >> 16) & 1u)) >> 16);
}

// ---------------- BN stats ----------------
__global__ __launch_bounds__(256) void k_bnstats(const float* __restrict__ x,
                                                 float* __restrict__ S1,
                                                 float* __restrict__ S2) {
  int c = threadIdx.x;
  float s1 = 0.f, s2 = 0.f;
  for (int r = blockIdx.x; r < NN; r += gridDim.x) {
    float v = x[r * IC + c];
    s1 += v;
    s2 = fmaf(v, v, s2);
  }
  atomicAdd(&S1[c], s1);
  atomicAdd(&S2[c], s2);
}

__global__ __launch_bounds__(256) void k_bnfin(const float* __restrict__ S1,
                                               const float* __restrict__ S2,
                                               const float* __restrict__ g,
                                               const float* __restrict__ b,
                                               float* __restrict__ scale,
                                               float* __restrict__ shift) {
  int c = threadIdx.x;
  float mu = S1[c] * (1.f / NN);
  float var = S2[c] * (1.f / NN) - mu * mu;
  float s = g[c] / sqrtf(var + EPS);
  scale[c] = s;
  shift[c] = b[c] - mu * s;
}

// ---------------- weight prep: fragment-ordered bf16 hi/lo ----------------
// layout: id = ((ks*32 + ntg)*64 + lane)*8 + j ; k = ks*32+(lane>>4)*8+j ; n = ntg*16+(lane&15)
__global__ __launch_bounds__(256) void k_prepB(const float* __restrict__ Wlin,
                                               const float* __restrict__ Wcon,
                                               unsigned short* __restrict__ Bfh,
                                               unsigned short* __restrict__ Bfl) {
  int id = blockIdx.x * 256 + threadIdx.x;  // < 131072
  int j = id & 7, lane = (id >> 3) & 63, nt = (id >> 9) & 31, ks = id >> 14;
  int k = ks * 32 + ((lane >> 4) << 3) + j;
  int n = nt * 16 + (lane & 15);
  float v = (n < 256) ? Wlin[k * 256 + n] : Wcon[k * 256 + (n - 256)];
  unsigned short h = f2bf(v);
  Bfh[id] = h;
  Bfl[id] = f2bf(v - b2f(h));
}

// ---------------- MFMA dual GEMM: [ylin(fp32) | h(bf16)] = bn(x) @ [Wlin|Wcon] -----
// grid (8, 391): blockIdx.x = 64-col slice (0-3 -> ylin, 4-7 -> h), blockIdx.y = 128 rows
__global__ __launch_bounds__(256) void k_gemm(const float* __restrict__ x,
                                              const float* __restrict__ scale,
                                              const float* __restrict__ shift,
                                              const unsigned short* __restrict__ Bfh,
                                              const unsigned short* __restrict__ Bfl,
                                              float* __restrict__ ylin,
                                              unsigned short* __restrict__ hbf) {
  __shared__ unsigned short Ah[4096], Al[4096];  // [mtile(8)][lane(64)][j(8)]
  __shared__ float sc[256], sh[256];
  const int tid = threadIdx.x;
  const int nb = blockIdx.x;
  const int row0 = blockIdx.y * 128;
  const int wave = tid >> 6, lane = tid & 63;
  sc[tid] = scale[tid];
  sh[tid] = shift[tid];
  __syncthreads();
  const float4* x4 = (const float4*)x;
  const short8* Bh8 = (const short8*)Bfh;
  const short8* Bl8 = (const short8*)Bfl;
  f32x4 acc[2][4];
#pragma unroll
  for (int i = 0; i < 2; ++i)
#pragma unroll
    for (int j = 0; j < 4; ++j) acc[i][j] = (f32x4){0.f, 0.f, 0.f, 0.f};

  for (int ks = 0; ks < 8; ++ks) {
    const int k0 = ks * 32;
#pragma unroll
    for (int rep = 0; rep < 2; ++rep) {
      int slot = rep * 256 + tid;
      int m = slot & 127, kg = slot >> 7;
      int r = row0 + m;
      int c0 = k0 + kg * 8;
      float v[8];
      if (r < NN) {
        int base = (r * IC + c0) >> 2;
        float4 fa = x4[base], fb = x4[base + 1];
        v[0] = fa.x; v[1] = fa.y; v[2] = fa.z; v[3] = fa.w;
        v[4] = fb.x; v[5] = fb.y; v[6] = fb.z; v[7] = fb.w;
#pragma unroll
        for (int j = 0; j < 8; ++j) v[j] = fmaf(v[j], sc[c0 + j], sh[c0 + j]);
      } else {
#pragma unroll
        for (int j = 0; j < 8; ++j) v[j] = 0.f;
      }
      unsigned ph[4], pl[4];
#pragma unroll
      for (int j = 0; j < 4; ++j) {
        unsigned short h0 = f2bf(v[2 * j]), h1 = f2bf(v[2 * j + 1]);
        unsigned short l0 = f2bf(v[2 * j] - b2f(h0));
        unsigned short l1 = f2bf(v[2 * j + 1] - b2f(h1));
        ph[j] = (unsigned)h0 | ((unsigned)h1 << 16);
        pl[j] = (unsigned)l0 | ((unsigned)l1 << 16);
      }
      int mt = m >> 4;
      int lt = (m & 15) | (kg << 4);
      int addr = (mt * 64 + lt) * 8;
      *(uint4*)&Ah[addr] = make_uint4(ph[0], ph[1], ph[2], ph[3]);
      *(uint4*)&Al[addr] = make_uint4(pl[0], pl[1], pl[2], pl[3]);
    }
    __syncthreads();
    short8 bh[4], bl[4];
#pragma unroll
    for (int nt = 0; nt < 4; ++nt) {
      int off = (ks * 32 + nb * 4 + nt) * 64 + lane;
      bh[nt] = Bh8[off];
      bl[nt] = Bl8[off];
    }
    short8 ah[2], alo[2];
#pragma unroll
    for (int mt2 = 0; mt2 < 2; ++mt2) {
      int addr = ((wave * 2 + mt2) * 64 + lane) * 8;
      ah[mt2] = *(const short8*)&Ah[addr];
      alo[mt2] = *(const short8*)&Al[addr];
    }
#pragma unroll
    for (int mt2 = 0; mt2 < 2; ++mt2)
#pragma unroll
      for (int nt = 0; nt < 4; ++nt) {
        acc[mt2][nt] = __builtin_amdgcn_mfma_f32_16x16x32_bf16(ah[mt2], bh[nt], acc[mt2][nt], 0, 0, 0);
        acc[mt2][nt] = __builtin_amdgcn_mfma_f32_16x16x32_bf16(alo[mt2], bh[nt], acc[mt2][nt], 0, 0, 0);
        acc[mt2][nt] = __builtin_amdgcn_mfma_f32_16x16x32_bf16(ah[mt2], bl[nt], acc[mt2][nt], 0, 0, 0);
      }
    __syncthreads();
  }
  // epilogue: C/D layout col=lane&15, row=(lane>>4)*4+reg
  const int colq = lane & 15, quad = lane >> 4;
#pragma unroll
  for (int mt2 = 0; mt2 < 2; ++mt2) {
    int rbase = row0 + wave * 32 + mt2 * 16 + quad * 4;
#pragma unroll
    for (int reg = 0; reg < 4; ++reg) {
      int r = rbase + reg;
      if (r < NN) {
        if (nb < 4) {
#pragma unroll
          for (int nt = 0; nt < 4; ++nt)
            ylin[r * IC + nb * 64 + nt * 16 + colq] = acc[mt2][nt][reg];
        } else {
#pragma unroll
          for (int nt = 0; nt < 4; ++nt)
            hbf[r * IC + (nb - 4) * 64 + nt * 16 + colq] = f2bf(acc[mt2][nt][reg]);
        }
      }
    }
  }
}

// ---------------- attention logits from bf16 h ----------------
__global__ __launch_bounds__(256) void k_alpha(const uint4* __restrict__ hq8,
                                               const float4* __restrict__ as4,
                                               const float4* __restrict__ ad4,
                                               float* __restrict__ als,
                                               float* __restrict__ ald) {
  int gid = blockIdx.x * 256 + threadIdx.x;  // 32 lanes per node
  int node = gid >> 5, l5 = gid & 31;
  int head = l5 >> 3, li = l5 & 7;
  uint4 hv = hq8[node * 32 + l5];
  float h0 = b2f((unsigned short)(hv.x & 0xffff)), h1 = b2f((unsigned short)(hv.x >> 16));
  float h2 = b2f((unsigned short)(hv.y & 0xffff)), h3 = b2f((unsigned short)(hv.y >> 16));
  float h4 = b2f((unsigned short)(hv.z & 0xffff)), h5 = b2f((unsigned short)(hv.z >> 16));
  float h6 = b2f((unsigned short)(hv.w & 0xffff)), h7 = b2f((unsigned short)(hv.w >> 16));
  float4 aA = as4[l5 * 2], aB = as4[l5 * 2 + 1];
  float4 dA = ad4[l5 * 2], dB = ad4[l5 * 2 + 1];
  float ps = h0 * aA.x + h1 * aA.y + h2 * aA.z + h3 * aA.w
           + h4 * aB.x + h5 * aB.y + h6 * aB.z + h7 * aB.w;
  float pd = h0 * dA.x + h1 * dA.y + h2 * dA.z + h3 * dA.w
           + h4 * dB.x + h5 * dB.y + h6 * dB.z + h7 * dB.w;
#pragma unroll
  for (int off = 1; off < 8; off <<= 1) {
    ps += __shfl_xor(ps, off, 64);
    pd += __shfl_xor(pd, off, 64);
  }
  if (li == 0) {
    als[node * 4 + head] = ps;
    ald[node * 4 + head] = pd;
  }
}

// ---------------- counting sort by dst (hierarchical scan) ----------------
__global__ __launch_bounds__(256) void k_hist(const int* __restrict__ dst,
                                              int* __restrict__ counts) {
  int e = blockIdx.x * 256 + threadIdx.x;
  atomicAdd(&counts[dst[e]], 1);
}

__global__ __launch_bounds__(1024) void k_scanA(const int* __restrict__ counts,
                                                int* __restrict__ start,
                                                int* __restrict__ bsum) {
  __shared__ int buf[1024];
  int b = blockIdx.x, tid = threadIdx.x;
  int i = b * 1024 + tid;
  int v = (i < NN) ? counts[i] : 0;
  buf[tid] = v;
  __syncthreads();
  for (int off = 1; off < 1024; off <<= 1) {
    int t = (tid >= off) ? buf[tid - off] : 0;
    __syncthreads();
    buf[tid] += t;
    __syncthreads();
  }
  if (i < NN) start[i] = buf[tid] - v;  // chunk-local exclusive
  if (tid == 1023) bsum[b] = buf[1023];
}

__global__ __launch_bounds__(64) void k_scanB(const int* __restrict__ bsum,
                                              int* __restrict__ boff,
                                              int* __restrict__ start) {
  int l = threadIdx.x;
  int v = (l < 49) ? bsum[l] : 0;
  int incl = v;
#pragma unroll
  for (int off = 1; off < 64; off <<= 1) {
    int t = __shfl_up(incl, off, 64);
    if (l >= off) incl += t;
  }
  if (l < 49) boff[l] = incl - v;
  if (l == 48) start[NN] = incl;
}

__global__ __launch_bounds__(1024) void k_scanC(int* __restrict__ start,
                                                int* __restrict__ cursor,
                                                const int* __restrict__ boff) {
  int i = blockIdx.x * 1024 + threadIdx.x;
  if (i < NN) {
    int s = start[i] + boff[blockIdx.x];
    start[i] = s;
    cursor[i] = s;
  }
}

__global__ __launch_bounds__(256) void k_scatter(const int* __restrict__ src,
                                                 const int* __restrict__ dst,
                                                 int* __restrict__ cursor,
                                                 int* __restrict__ srcs) {
  int e = blockIdx.x * 256 + threadIdx.x;
  int pos = atomicAdd(&cursor[dst[e]], 1);
  srcs[pos] = src[e];
}

// ---------------- layer-1 aggregation: wave/node, fused softmax + epilogue --------
__global__ __launch_bounds__(256) void k_agg(const ushort4* __restrict__ hq,
                                             float4* __restrict__ x14,
                                             const float* __restrict__ als,
                                             const float4* __restrict__ ald4,
                                             const int* __restrict__ start,
                                             const int* __restrict__ srcs,
                                             const float4* __restrict__ b1,
                                             const float4* __restrict__ b2) {
  int n = (blockIdx.x * 256 + threadIdx.x) >> 6;
  int lane = threadIdx.x & 63;
  int head = lane >> 4;
  int s = start[n], t = start[n + 1];
  const float4* als4 = (const float4*)als;
  float4 aldv = ald4[n];
  // pass 1: lane-parallel segment max (lrelu monotonic -> max of lrelu)
  float m0 = -INFINITY, m1 = -INFINITY, m2 = -INFINITY, m3 = -INFINITY;
  for (int i = s + lane; i < t; i += 64) {
    int sv = srcs[i];
    float4 a = als4[sv];
    m0 = fmaxf(m0, lrelu(a.x + aldv.x));
    m1 = fmaxf(m1, lrelu(a.y + aldv.y));
    m2 = fmaxf(m2, lrelu(a.z + aldv.z));
    m3 = fmaxf(m3, lrelu(a.w + aldv.w));
  }
#pragma unroll
  for (int off = 1; off < 64; off <<= 1) {
    m0 = fmaxf(m0, __shfl_xor(m0, off, 64));
    m1 = fmaxf(m1, __shfl_xor(m1, off, 64));
    m2 = fmaxf(m2, __shfl_xor(m2, off, 64));
    m3 = fmaxf(m3, __shfl_xor(m3, off, 64));
  }
  float mh = (head == 0) ? m0 : (head == 1) ? m1 : (head == 2) ? m2 : m3;
  float aldh = (head == 0) ? aldv.x : (head == 1) ? aldv.y : (head == 2) ? aldv.z : aldv.w;
  // pass 2: serial-broadcast accumulate (den identical across a head's 16 lanes)
  float a0 = 0.f, a1 = 0.f, a2 = 0.f, a3 = 0.f, den = 0.f;
  for (int base = s; base < t; base += 64) {
    int idx = base + lane;
    int svb = (idx < t) ? srcs[idx] : 0;
    int cnt = min(64, t - base);
    for (int j = 0; j < cnt; ++j) {
      int sv = __shfl(svb, j, 64);
      float av = als[sv * 4 + head];
      float p = __expf(lrelu(av + aldh) - mh);
      ushort4 hv = hq[sv * 64 + lane];
      a0 = fmaf(p, b2f(hv.x), a0);
      a1 = fmaf(p, b2f(hv.y), a1);
      a2 = fmaf(p, b2f(hv.z), a2);
      a3 = fmaf(p, b2f(hv.w), a3);
      den += p;
    }
  }
  float inv = 1.f / (den + 1e-16f);
  float4 yl = x14[n * 64 + lane];
  float4 bb1 = b1[lane], bb2 = b2[lane];
  float4 r;
  r.x = fmaxf(fmaf(a0, inv, yl.x + bb1.x + bb2.x), 0.f);
  r.y = fmaxf(fmaf(a1, inv, yl.y + bb1.y + bb2.y), 0.f);
  r.z = fmaxf(fmaf(a2, inv, yl.z + bb1.z + bb2.z), 0.f);
  r.w = fmaxf(fmaf(a3, inv, yl.w + bb1.w + bb2.w), 0.f);
  x14[n * 64 + lane] = r;
}

// ---------------- layer 2 node kernel ----------------
__global__ __launch_bounds__(256) void k_node2(const float4* __restrict__ x14,
                                               const float4* __restrict__ scale4,
                                               const float4* __restrict__ shift4,
                                               const float4* __restrict__ Wl4,
                                               const float4* __restrict__ Wc4,
                                               const float* __restrict__ a3s,
                                               const float* __restrict__ a3d,
                                               float* __restrict__ y3,
                                               float* __restrict__ h3,
                                               float* __restrict__ al3s,
                                               float* __restrict__ al3d) {
  int n = (blockIdx.x * 256 + threadIdx.x) >> 6;
  int lane = threadIdx.x & 63;
  float4 xv = x14[n * 64 + lane];
  float4 sc = scale4[lane], sh = shift4[lane];
  float x0 = fmaf(xv.x, sc.x, sh.x);
  float x1 = fmaf(xv.y, sc.y, sh.y);
  float x2 = fmaf(xv.z, sc.z, sh.z);
  float x3 = fmaf(xv.w, sc.w, sh.w);
  float4 wa = Wl4[lane * 2], wb = Wl4[lane * 2 + 1];
  float y0 = x0 * wa.x + x1 * wa.z + x2 * wb.x + x3 * wb.z;
  float y1 = x0 * wa.y + x1 * wa.w + x2 * wb.y + x3 * wb.w;
  float4 ca = Wc4[lane * 2], cb = Wc4[lane * 2 + 1];
  float g0 = x0 * ca.x + x1 * ca.z + x2 * cb.x + x3 * cb.z;
  float g1 = x0 * ca.y + x1 * ca.w + x2 * cb.y + x3 * cb.w;
#pragma unroll
  for (int off = 1; off < 64; off <<= 1) {
    y0 += __shfl_xor(y0, off, 64);
    y1 += __shfl_xor(y1, off, 64);
    g0 += __shfl_xor(g0, off, 64);
    g1 += __shfl_xor(g1, off, 64);
  }
  if (lane == 0) {
    y3[2 * n] = y0;
    y3[2 * n + 1] = y1;
    h3[2 * n] = g0;
    h3[2 * n + 1] = g1;
    al3s[n] = g0 * a3s[0] + g1 * a3s[1];
    al3d[n] = g0 * a3d[0] + g1 * a3d[1];
  }
}

// ---------------- layer 2 softmax-aggregate + output (16 lanes / node) ----------
__global__ __launch_bounds__(256) void k_final(const int* __restrict__ start,
                                               const int* __restrict__ srcs,
                                               const float* __restrict__ al3s,
                                               const float* __restrict__ al3d,
                                               const float2* __restrict__ h32,
                                               const float* __restrict__ y3,
                                               const float* __restrict__ l3b,
                                               const float* __restrict__ c3b,
                                               float* __restrict__ out) {
  int tid = threadIdx.x;
  int n = blockIdx.x * 16 + (tid >> 4);
  int li = tid & 15;
  int s = start[n], t = start[n + 1];
  float ad = al3d[n];
  float m = -INFINITY;
  for (int i = s + li; i < t; i += 16) m = fmaxf(m, lrelu(al3s[srcs[i]] + ad));
#pragma unroll
  for (int off = 1; off < 16; off <<= 1) m = fmaxf(m, __shfl_xor(m, off, 64));
  float den = 0.f, a0 = 0.f, a1 = 0.f;
  for (int i = s + li; i < t; i += 16) {
    int sv = srcs[i];
    float p = __expf(lrelu(al3s[sv] + ad) - m);
    float2 hv = h32[sv];
    den += p;
    a0 = fmaf(p, hv.x, a0);
    a1 = fmaf(p, hv.y, a1);
  }
#pragma unroll
  for (int off = 1; off < 16; off <<= 1) {
    den += __shfl_xor(den, off, 64);
    a0 += __shfl_xor(a0, off, 64);
    a1 += __shfl_xor(a1, off, 64);
  }
  if (li == 0) {
    float inv = 1.f / (den + 1e-16f);
    out[2 * n] = fmaxf(y3[2 * n] + l3b[0] + c3b[0] + a0 * inv, 0.f);
    out[2 * n + 1] = fmaxf(y3[2 * n + 1] + l3b[1] + c3b[1] + a1 * inv, 0.f);
  }
}

extern "C" void kernel_launch(void* const* d_in, const int* in_sizes, int n_in,
                              void* d_out, int out_size, void* d_ws, size_t ws_size,
                              hipStream_t stream) {
  const float* x = (const float*)d_in[0];
  const int* ei = (const int*)d_in[1];
  const float* bn1_g = (const float*)d_in[2];
  const float* bn1_b = (const float*)d_in[3];
  const float* lin1_W = (const float*)d_in[4];
  const float* lin1_b = (const float*)d_in[5];
  const float* con1_W = (const float*)d_in[6];
  const float* con1_as = (const float*)d_in[7];
  const float* con1_ad = (const float*)d_in[8];
  const float* con1_b = (const float*)d_in[9];
  const float* bn3_g = (const float*)d_in[10];
  const float* bn3_b = (const float*)d_in[11];
  const float* lin3_W = (const float*)d_in[12];
  const float* lin3_b = (const float*)d_in[13];
  const float* con3_W = (const float*)d_in[14];
  const float* con3_as = (const float*)d_in[15];
  const float* con3_ad = (const float*)d_in[16];
  const float* con3_b = (const float*)d_in[17];
  float* ws = (float*)d_ws;
  const int* srcA = ei;
  const int* dstA = ei + NE;

  float* scale = ws + OFF_SCALE;
  float* shift = ws + OFF_SHIFT;
  float* S1 = ws + OFF_S1;
  float* S2 = ws + OFF_S2;
  int* counts = (int*)(ws + OFF_COUNTS);
  int* cursor = (int*)(ws + OFF_CURSOR);
  int* start = (int*)(ws + OFF_START);
  int* bsum = (int*)(ws + OFF_BSUM);
  int* boff = (int*)(ws + OFF_BOFF);
  float* als = ws + OFF_ALS;
  float* ald = ws + OFF_ALD;
  int* srcs = (int*)(ws + OFF_SRCS);
  float* y3 = ws + OFF_Y3;
  float* h3 = ws + OFF_H3;
  float* al3s = ws + OFF_AL3S;
  float* al3d = ws + OFF_AL3D;
  unsigned short* Bfh = (unsigned short*)(ws + OFF_BFH);
  unsigned short* Bfl = (unsigned short*)(ws + OFF_BFL);
  unsigned short* hbf = (unsigned short*)(ws + OFF_HBF);
  float* ylin = ws + OFF_YLIN;  // becomes x1 in place

  hipMemsetAsync(ws + OFF_S1, 0, (size_t)(ZERO_END - OFF_S1) * sizeof(float), stream);

  // ---- layer 1 ----
  k_prepB<<<512, 256, 0, stream>>>(lin1_W, con1_W, Bfh, Bfl);
  k_bnstats<<<256, 256, 0, stream>>>(x, S1, S2);
  k_bnfin<<<1, 256, 0, stream>>>(S1, S2, bn1_g, bn1_b, scale, shift);
  k_gemm<<<dim3(8, 391), 256, 0, stream>>>(x, scale, shift, Bfh, Bfl, ylin, hbf);
  k_alpha<<<6250, 256, 0, stream>>>((const uint4*)hbf, (const float4*)con1_as,
                                    (const float4*)con1_ad, als, ald);
  k_hist<<<3125, 256, 0, stream>>>(dstA, counts);
  k_scanA<<<49, 1024, 0, stream>>>(counts, start, bsum);
  k_scanB<<<1, 64, 0, stream>>>(bsum, boff, start);
  k_scanC<<<49, 1024, 0, stream>>>(start, cursor, boff);
  k_scatter<<<3125, 256, 0, stream>>>(srcA, dstA, cursor, srcs);
  k_agg<<<12500, 256, 0, stream>>>((const ushort4*)hbf, (float4*)ylin, als,
                                   (const float4*)ald, start, srcs,
                                   (const float4*)lin1_b, (const float4*)con1_b);

  // ---- layer 2 ----
  hipMemsetAsync(ws + OFF_S1, 0, 512 * sizeof(float), stream);
  k_bnstats<<<256, 256, 0, stream>>>(ylin, S1, S2);
  k_bnfin<<<1, 256, 0, stream>>>(S1, S2, bn3_g, bn3_b, scale, shift);
  k_node2<<<12500, 256, 0, stream>>>((const float4*)ylin, (const float4*)scale,
                                     (const float4*)shift, (const float4*)lin3_W,
                                     (const float4*)con3_W, con3_as, con3_ad, y3, h3,
                                     al3s, al3d);
  k_final<<<3125, 256, 0, stream>>>(start, srcs, al3s, al3d, (const float2*)h3, y3,
                                    lin3_b, con3_b, (float*)d_out);
}

// Round 3
// 472.738 us; speedup vs baseline: 2.3739x; 1.1680x over previous
//
#include <hip/hip_runtime.h>
#include <math.h>

#define NN 50000
#define NE 800000
#define IC 256
#define EPS 1e-5f

typedef __attribute__((ext_vector_type(8))) short short8;   // 8 bf16 (4 VGPRs)
typedef __attribute__((ext_vector_type(4))) float f32x4;    // MFMA acc

// ---------------- ws layout (float offsets) ----------------
enum : int {
  OFF_SCALE  = 0,                        // [256]
  OFF_SHIFT  = 256,                      // [256]
  OFF_S1     = 512,                      // [256] zeroed
  OFF_S2     = 768,                      // [256] zeroed
  OFF_COUNTS = 1024,                     // int[NN] zeroed
  ZERO_END   = OFF_COUNTS + 50000,
  OFF_CURSOR = ZERO_END,                 // int[NN]
  OFF_START  = OFF_CURSOR + 50000,       // int[NN+1] (pad 50004)
  OFF_BSUM   = OFF_START + 50004,        // int[64]
  OFF_BOFF   = OFF_BSUM + 64,            // int[64]
  OFF_ALS    = OFF_BOFF + 64,            // [NN*4]
  OFF_ALD    = OFF_ALS + 200000,         // [NN*4]
  OFF_SRCS   = OFF_ALD + 200000,         // int[NE]
  OFF_Y3     = OFF_SRCS + 800000,        // [NN*2]
  OFF_H3     = OFF_Y3 + 100000,          // [NN*2]
  OFF_AL3S   = OFF_H3 + 100000,          // [NN]
  OFF_AL3D   = OFF_AL3S + 50000,         // [NN]
  OFF_BFH    = OFF_AL3D + 50000,         // ushort[131072] = 65536 floats
  OFF_BFL    = OFF_BFH + 65536,          // ushort[131072]
  OFF_HBF    = OFF_BFL + 65536,          // ushort[NN*256] = 6.4M floats
  OFF_YLIN   = OFF_HBF + 6400000,        // [NN*256] fp32; becomes x1 in-place
  WS_FLOATS  = OFF_YLIN + 12800000       // ~84 MB
};

__device__ __forceinline__ float lrelu(float s) { return s > 0.f ? s : 0.2f * s; }
__device__ __forceinline__ float b2f(unsigned short u) {
  return __uint_as_float(((unsigned)u) << 16);
}
__device__ __forceinline__ unsigned short f2bf(float f) {  // RNE
  unsigned u = __float_as_uint(f);
  return (unsigned short)((u + 0x7fffu + ((u >> 16) & 1u)) >> 16);
}

// ---------------- BN stats ----------------
__global__ __launch_bounds__(256) void k_bnstats(const float* __restrict__ x,
                                                 float* __restrict__ S1,
                                                 float* __restrict__ S2) {
  int c = threadIdx.x;
  float s1 = 0.f, s2 = 0.f;
  for (int r = blockIdx.x; r < NN; r += gridDim.x) {
    float v = x[r * IC + c];
    s1 += v;
    s2 = fmaf(v, v, s2);
  }
  atomicAdd(&S1[c], s1);
  atomicAdd(&S2[c], s2);
}

__global__ __launch_bounds__(256) void k_bnfin(const float* __restrict__ S1,
                                               const float* __restrict__ S2,
                                               const float* __restrict__ g,
                                               const float* __restrict__ b,
                                               float* __restrict__ scale,
                                               float* __restrict__ shift) {
  int c = threadIdx.x;
  float mu = S1[c] * (1.f / NN);
  float var = S2[c] * (1.f / NN) - mu * mu;
  float s = g[c] / sqrtf(var + EPS);
  scale[c] = s;
  shift[c] = b[c] - mu * s;
}

// ---------------- weight prep: fragment-ordered bf16 hi/lo ----------------
// id = ((ks*32 + ntg)*64 + lane)*8 + j ; k = ks*32+(lane>>4)*8+j ; n = ntg*16+(lane&15)
__global__ __launch_bounds__(256) void k_prepB(const float* __restrict__ Wlin,
                                               const float* __restrict__ Wcon,
                                               unsigned short* __restrict__ Bfh,
                                               unsigned short* __restrict__ Bfl) {
  int id = blockIdx.x * 256 + threadIdx.x;  // < 131072
  int j = id & 7, lane = (id >> 3) & 63, nt = (id >> 9) & 31, ks = id >> 14;
  int k = ks * 32 + ((lane >> 4) << 3) + j;
  int n = nt * 16 + (lane & 15);
  float v = (n < 256) ? Wlin[k * 256 + n] : Wcon[k * 256 + (n - 256)];
  unsigned short h = f2bf(v);
  Bfh[id] = h;
  Bfl[id] = f2bf(v - b2f(h));
}

// ---------------- MFMA dual GEMM, x read once ----------------
// grid 782: block = 64 rows x 512 cols. wave w owns cols [128w,128w+128).
// waves 0-1 -> ylin (fp32), waves 2-3 -> hbf (bf16).
__global__ __launch_bounds__(256, 2) void k_gemm(const float* __restrict__ x,
                                                 const float* __restrict__ scale,
                                                 const float* __restrict__ shift,
                                                 const unsigned short* __restrict__ Bfh,
                                                 const unsigned short* __restrict__ Bfl,
                                                 float* __restrict__ ylin,
                                                 unsigned short* __restrict__ hbf) {
  __shared__ unsigned short Ah[2048], Al[2048];  // 64 rows x 32 k, fragment-ordered
  __shared__ float sc[256], sh[256];
  const int tid = threadIdx.x;
  const int row0 = blockIdx.x * 64;
  const int wave = tid >> 6, lane = tid & 63;
  sc[tid] = scale[tid];
  sh[tid] = shift[tid];
  const float4* x4 = (const float4*)x;
  const short8* Bh8 = (const short8*)Bfh;
  const short8* Bl8 = (const short8*)Bfl;
  f32x4 acc[4][8];
#pragma unroll
  for (int i = 0; i < 4; ++i)
#pragma unroll
    for (int j = 0; j < 8; ++j) acc[i][j] = (f32x4){0.f, 0.f, 0.f, 0.f};

  // staging role: thread -> row m = tid>>2, k-octet kg = tid&3
  const int m = tid >> 2, kg = tid & 3;
  const int r = row0 + m;
  const int aaddr = (((m >> 4) * 64) + ((m & 15) | (kg << 4))) * 8;
  __syncthreads();  // sc/sh visible

  for (int ks = 0; ks < 8; ++ks) {
    const int c0 = ks * 32 + kg * 8;
    float v[8];
    if (r < NN) {
      int base = (r * IC + c0) >> 2;
      float4 fa = x4[base], fb = x4[base + 1];
      v[0] = fa.x; v[1] = fa.y; v[2] = fa.z; v[3] = fa.w;
      v[4] = fb.x; v[5] = fb.y; v[6] = fb.z; v[7] = fb.w;
#pragma unroll
      for (int j = 0; j < 8; ++j) v[j] = fmaf(v[j], sc[c0 + j], sh[c0 + j]);
    } else {
#pragma unroll
      for (int j = 0; j < 8; ++j) v[j] = 0.f;
    }
    unsigned ph[4], pl[4];
#pragma unroll
    for (int j = 0; j < 4; ++j) {
      unsigned short h0 = f2bf(v[2 * j]), h1 = f2bf(v[2 * j + 1]);
      unsigned short l0 = f2bf(v[2 * j] - b2f(h0));
      unsigned short l1 = f2bf(v[2 * j + 1] - b2f(h1));
      ph[j] = (unsigned)h0 | ((unsigned)h1 << 16);
      pl[j] = (unsigned)l0 | ((unsigned)l1 << 16);
    }
    *(uint4*)&Ah[aaddr] = make_uint4(ph[0], ph[1], ph[2], ph[3]);
    *(uint4*)&Al[aaddr] = make_uint4(pl[0], pl[1], pl[2], pl[3]);
    __syncthreads();

    short8 ah[4], alo[4];
#pragma unroll
    for (int mt = 0; mt < 4; ++mt) {
      ah[mt] = *(const short8*)&Ah[(mt * 64 + lane) * 8];
      alo[mt] = *(const short8*)&Al[(mt * 64 + lane) * 8];
    }
#pragma unroll
    for (int nt = 0; nt < 8; ++nt) {
      int boff = (ks * 32 + wave * 8 + nt) * 64 + lane;
      short8 bh = Bh8[boff];
      short8 bl = Bl8[boff];
#pragma unroll
      for (int mt = 0; mt < 4; ++mt) {
        acc[mt][nt] = __builtin_amdgcn_mfma_f32_16x16x32_bf16(ah[mt], bh, acc[mt][nt], 0, 0, 0);
        acc[mt][nt] = __builtin_amdgcn_mfma_f32_16x16x32_bf16(alo[mt], bh, acc[mt][nt], 0, 0, 0);
        acc[mt][nt] = __builtin_amdgcn_mfma_f32_16x16x32_bf16(ah[mt], bl, acc[mt][nt], 0, 0, 0);
      }
    }
    __syncthreads();
  }
  // epilogue: C/D layout col=lane&15, row=(lane>>4)*4+reg
  const int colq = lane & 15, quad = lane >> 4;
#pragma unroll
  for (int mt = 0; mt < 4; ++mt) {
#pragma unroll
    for (int reg = 0; reg < 4; ++reg) {
      int rr = row0 + mt * 16 + quad * 4 + reg;
      if (rr < NN) {
        if (wave < 2) {
#pragma unroll
          for (int nt = 0; nt < 8; ++nt)
            ylin[rr * IC + wave * 128 + nt * 16 + colq] = acc[mt][nt][reg];
        } else {
#pragma unroll
          for (int nt = 0; nt < 8; ++nt)
            hbf[rr * IC + (wave - 2) * 128 + nt * 16 + colq] = f2bf(acc[mt][nt][reg]);
        }
      }
    }
  }
}

// ---------------- attention logits from bf16 h ----------------
__global__ __launch_bounds__(256) void k_alpha(const uint4* __restrict__ hq8,
                                               const float4* __restrict__ as4,
                                               const float4* __restrict__ ad4,
                                               float* __restrict__ als,
                                               float* __restrict__ ald) {
  int gid = blockIdx.x * 256 + threadIdx.x;  // 32 lanes per node
  int node = gid >> 5, l5 = gid & 31;
  int head = l5 >> 3, li = l5 & 7;
  uint4 hv = hq8[node * 32 + l5];
  float h0 = b2f((unsigned short)(hv.x & 0xffff)), h1 = b2f((unsigned short)(hv.x >> 16));
  float h2 = b2f((unsigned short)(hv.y & 0xffff)), h3 = b2f((unsigned short)(hv.y >> 16));
  float h4 = b2f((unsigned short)(hv.z & 0xffff)), h5 = b2f((unsigned short)(hv.z >> 16));
  float h6 = b2f((unsigned short)(hv.w & 0xffff)), h7 = b2f((unsigned short)(hv.w >> 16));
  float4 aA = as4[l5 * 2], aB = as4[l5 * 2 + 1];
  float4 dA = ad4[l5 * 2], dB = ad4[l5 * 2 + 1];
  float ps = h0 * aA.x + h1 * aA.y + h2 * aA.z + h3 * aA.w
           + h4 * aB.x + h5 * aB.y + h6 * aB.z + h7 * aB.w;
  float pd = h0 * dA.x + h1 * dA.y + h2 * dA.z + h3 * dA.w
           + h4 * dB.x + h5 * dB.y + h6 * dB.z + h7 * dB.w;
#pragma unroll
  for (int off = 1; off < 8; off <<= 1) {
    ps += __shfl_xor(ps, off, 64);
    pd += __shfl_xor(pd, off, 64);
  }
  if (li == 0) {
    als[node * 4 + head] = ps;
    ald[node * 4 + head] = pd;
  }
}

// ---------------- counting sort by dst (hierarchical scan) ----------------
__global__ __launch_bounds__(256) void k_hist(const int* __restrict__ dst,
                                              int* __restrict__ counts) {
  int e = blockIdx.x * 256 + threadIdx.x;
  atomicAdd(&counts[dst[e]], 1);
}

__global__ __launch_bounds__(1024) void k_scanA(const int* __restrict__ counts,
                                                int* __restrict__ start,
                                                int* __restrict__ bsum) {
  __shared__ int buf[1024];
  int b = blockIdx.x, tid = threadIdx.x;
  int i = b * 1024 + tid;
  int v = (i < NN) ? counts[i] : 0;
  buf[tid] = v;
  __syncthreads();
  for (int off = 1; off < 1024; off <<= 1) {
    int t = (tid >= off) ? buf[tid - off] : 0;
    __syncthreads();
    buf[tid] += t;
    __syncthreads();
  }
  if (i < NN) start[i] = buf[tid] - v;  // chunk-local exclusive
  if (tid == 1023) bsum[b] = buf[1023];
}

__global__ __launch_bounds__(64) void k_scanB(const int* __restrict__ bsum,
                                              int* __restrict__ boff,
                                              int* __restrict__ start) {
  int l = threadIdx.x;
  int v = (l < 49) ? bsum[l] : 0;
  int incl = v;
#pragma unroll
  for (int off = 1; off < 64; off <<= 1) {
    int t = __shfl_up(incl, off, 64);
    if (l >= off) incl += t;
  }
  if (l < 49) boff[l] = incl - v;
  if (l == 48) start[NN] = incl;
}

__global__ __launch_bounds__(1024) void k_scanC(int* __restrict__ start,
                                                int* __restrict__ cursor,
                                                const int* __restrict__ boff) {
  int i = blockIdx.x * 1024 + threadIdx.x;
  if (i < NN) {
    int s = start[i] + boff[blockIdx.x];
    start[i] = s;
    cursor[i] = s;
  }
}

__global__ __launch_bounds__(256) void k_scatter(const int* __restrict__ src,
                                                 const int* __restrict__ dst,
                                                 int* __restrict__ cursor,
                                                 int* __restrict__ srcs) {
  int e = blockIdx.x * 256 + threadIdx.x;
  int pos = atomicAdd(&cursor[dst[e]], 1);
  srcs[pos] = src[e];
}

// ---------------- layer-1 aggregation: wave/node, fused softmax + epilogue --------
__global__ __launch_bounds__(256) void k_agg(const ushort4* __restrict__ hq,
                                             float4* __restrict__ x14,
                                             const float* __restrict__ als,
                                             const float4* __restrict__ ald4,
                                             const int* __restrict__ start,
                                             const int* __restrict__ srcs,
                                             const float4* __restrict__ b1,
                                             const float4* __restrict__ b2) {
  int n = (blockIdx.x * 256 + threadIdx.x) >> 6;
  int lane = threadIdx.x & 63;
  int head = lane >> 4;
  int s = start[n], t = start[n + 1];
  const float4* als4 = (const float4*)als;
  float4 aldv = ald4[n];
  // pass 1: lane-parallel segment max (lrelu monotonic -> max of lrelu)
  float m0 = -INFINITY, m1 = -INFINITY, m2 = -INFINITY, m3 = -INFINITY;
  for (int i = s + lane; i < t; i += 64) {
    int sv = srcs[i];
    float4 a = als4[sv];
    m0 = fmaxf(m0, lrelu(a.x + aldv.x));
    m1 = fmaxf(m1, lrelu(a.y + aldv.y));
    m2 = fmaxf(m2, lrelu(a.z + aldv.z));
    m3 = fmaxf(m3, lrelu(a.w + aldv.w));
  }
#pragma unroll
  for (int off = 1; off < 64; off <<= 1) {
    m0 = fmaxf(m0, __shfl_xor(m0, off, 64));
    m1 = fmaxf(m1, __shfl_xor(m1, off, 64));
    m2 = fmaxf(m2, __shfl_xor(m2, off, 64));
    m3 = fmaxf(m3, __shfl_xor(m3, off, 64));
  }
  float mh = (head == 0) ? m0 : (head == 1) ? m1 : (head == 2) ? m2 : m3;
  float aldh = (head == 0) ? aldv.x : (head == 1) ? aldv.y : (head == 2) ? aldv.z : aldv.w;
  // pass 2: serial-broadcast accumulate
  float a0 = 0.f, a1 = 0.f, a2 = 0.f, a3 = 0.f, den = 0.f;
  for (int base = s; base < t; base += 64) {
    int idx = base + lane;
    int svb = (idx < t) ? srcs[idx] : 0;
    int cnt = min(64, t - base);
    for (int j = 0; j < cnt; ++j) {
      int sv = __shfl(svb, j, 64);
      float av = als[sv * 4 + head];
      float p = __expf(lrelu(av + aldh) - mh);
      ushort4 hv = hq[sv * 64 + lane];
      a0 = fmaf(p, b2f(hv.x), a0);
      a1 = fmaf(p, b2f(hv.y), a1);
      a2 = fmaf(p, b2f(hv.z), a2);
      a3 = fmaf(p, b2f(hv.w), a3);
      den += p;
    }
  }
  float inv = 1.f / (den + 1e-16f);
  float4 yl = x14[n * 64 + lane];
  float4 bb1 = b1[lane], bb2 = b2[lane];
  float4 r;
  r.x = fmaxf(fmaf(a0, inv, yl.x + bb1.x + bb2.x), 0.f);
  r.y = fmaxf(fmaf(a1, inv, yl.y + bb1.y + bb2.y), 0.f);
  r.z = fmaxf(fmaf(a2, inv, yl.z + bb1.z + bb2.z), 0.f);
  r.w = fmaxf(fmaf(a3, inv, yl.w + bb1.w + bb2.w), 0.f);
  x14[n * 64 + lane] = r;
}

// ---------------- layer 2 node kernel ----------------
__global__ __launch_bounds__(256) void k_node2(const float4* __restrict__ x14,
                                               const float4* __restrict__ scale4,
                                               const float4* __restrict__ shift4,
                                               const float4* __restrict__ Wl4,
                                               const float4* __restrict__ Wc4,
                                               const float* __restrict__ a3s,
                                               const float* __restrict__ a3d,
                                               float* __restrict__ y3,
                                               float* __restrict__ h3,
                                               float* __restrict__ al3s,
                                               float* __restrict__ al3d) {
  int n = (blockIdx.x * 256 + threadIdx.x) >> 6;
  int lane = threadIdx.x & 63;
  float4 xv = x14[n * 64 + lane];
  float4 sc = scale4[lane], sh = shift4[lane];
  float x0 = fmaf(xv.x, sc.x, sh.x);
  float x1 = fmaf(xv.y, sc.y, sh.y);
  float x2 = fmaf(xv.z, sc.z, sh.z);
  float x3 = fmaf(xv.w, sc.w, sh.w);
  float4 wa = Wl4[lane * 2], wb = Wl4[lane * 2 + 1];
  float y0 = x0 * wa.x + x1 * wa.z + x2 * wb.x + x3 * wb.z;
  float y1 = x0 * wa.y + x1 * wa.w + x2 * wb.y + x3 * wb.w;
  float4 ca = Wc4[lane * 2], cb = Wc4[lane * 2 + 1];
  float g0 = x0 * ca.x + x1 * ca.z + x2 * cb.x + x3 * cb.z;
  float g1 = x0 * ca.y + x1 * ca.w + x2 * cb.y + x3 * cb.w;
#pragma unroll
  for (int off = 1; off < 64; off <<= 1) {
    y0 += __shfl_xor(y0, off, 64);
    y1 += __shfl_xor(y1, off, 64);
    g0 += __shfl_xor(g0, off, 64);
    g1 += __shfl_xor(g1, off, 64);
  }
  if (lane == 0) {
    y3[2 * n] = y0;
    y3[2 * n + 1] = y1;
    h3[2 * n] = g0;
    h3[2 * n + 1] = g1;
    al3s[n] = g0 * a3s[0] + g1 * a3s[1];
    al3d[n] = g0 * a3d[0] + g1 * a3d[1];
  }
}

// ---------------- layer 2 softmax-aggregate + output (16 lanes / node) ----------
__global__ __launch_bounds__(256) void k_final(const int* __restrict__ start,
                                               const int* __restrict__ srcs,
                                               const float* __restrict__ al3s,
                                               const float* __restrict__ al3d,
                                               const float2* __restrict__ h32,
                                               const float* __restrict__ y3,
                                               const float* __restrict__ l3b,
                                               const float* __restrict__ c3b,
                                               float* __restrict__ out) {
  int tid = threadIdx.x;
  int n = blockIdx.x * 16 + (tid >> 4);
  int li = tid & 15;
  int s = start[n], t = start[n + 1];
  float ad = al3d[n];
  float m = -INFINITY;
  for (int i = s + li; i < t; i += 16) m = fmaxf(m, lrelu(al3s[srcs[i]] + ad));
#pragma unroll
  for (int off = 1; off < 16; off <<= 1) m = fmaxf(m, __shfl_xor(m, off, 64));
  float den = 0.f, a0 = 0.f, a1 = 0.f;
  for (int i = s + li; i < t; i += 16) {
    int sv = srcs[i];
    float p = __expf(lrelu(al3s[sv] + ad) - m);
    float2 hv = h32[sv];
    den += p;
    a0 = fmaf(p, hv.x, a0);
    a1 = fmaf(p, hv.y, a1);
  }
#pragma unroll
  for (int off = 1; off < 16; off <<= 1) {
    den += __shfl_xor(den, off, 64);
    a0 += __shfl_xor(a0, off, 64);
    a1 += __shfl_xor(a1, off, 64);
  }
  if (li == 0) {
    float inv = 1.f / (den + 1e-16f);
    out[2 * n] = fmaxf(y3[2 * n] + l3b[0] + c3b[0] + a0 * inv, 0.f);
    out[2 * n + 1] = fmaxf(y3[2 * n + 1] + l3b[1] + c3b[1] + a1 * inv, 0.f);
  }
}

extern "C" void kernel_launch(void* const* d_in, const int* in_sizes, int n_in,
                              void* d_out, int out_size, void* d_ws, size_t ws_size,
                              hipStream_t stream) {
  const float* x = (const float*)d_in[0];
  const int* ei = (const int*)d_in[1];
  const float* bn1_g = (const float*)d_in[2];
  const float* bn1_b = (const float*)d_in[3];
  const float* lin1_W = (const float*)d_in[4];
  const float* lin1_b = (const float*)d_in[5];
  const float* con1_W = (const float*)d_in[6];
  const float* con1_as = (const float*)d_in[7];
  const float* con1_ad = (const float*)d_in[8];
  const float* con1_b = (const float*)d_in[9];
  const float* bn3_g = (const float*)d_in[10];
  const float* bn3_b = (const float*)d_in[11];
  const float* lin3_W = (const float*)d_in[12];
  const float* lin3_b = (const float*)d_in[13];
  const float* con3_W = (const float*)d_in[14];
  const float* con3_as = (const float*)d_in[15];
  const float* con3_ad = (const float*)d_in[16];
  const float* con3_b = (const float*)d_in[17];
  float* ws = (float*)d_ws;
  const int* srcA = ei;
  const int* dstA = ei + NE;

  float* scale = ws + OFF_SCALE;
  float* shift = ws + OFF_SHIFT;
  float* S1 = ws + OFF_S1;
  float* S2 = ws + OFF_S2;
  int* counts = (int*)(ws + OFF_COUNTS);
  int* cursor = (int*)(ws + OFF_CURSOR);
  int* start = (int*)(ws + OFF_START);
  int* bsum = (int*)(ws + OFF_BSUM);
  int* boff = (int*)(ws + OFF_BOFF);
  float* als = ws + OFF_ALS;
  float* ald = ws + OFF_ALD;
  int* srcs = (int*)(ws + OFF_SRCS);
  float* y3 = ws + OFF_Y3;
  float* h3 = ws + OFF_H3;
  float* al3s = ws + OFF_AL3S;
  float* al3d = ws + OFF_AL3D;
  unsigned short* Bfh = (unsigned short*)(ws + OFF_BFH);
  unsigned short* Bfl = (unsigned short*)(ws + OFF_BFL);
  unsigned short* hbf = (unsigned short*)(ws + OFF_HBF);
  float* ylin = ws + OFF_YLIN;  // becomes x1 in place

  hipMemsetAsync(ws + OFF_S1, 0, (size_t)(ZERO_END - OFF_S1) * sizeof(float), stream);

  // ---- layer 1 ----
  k_prepB<<<512, 256, 0, stream>>>(lin1_W, con1_W, Bfh, Bfl);
  k_bnstats<<<1024, 256, 0, stream>>>(x, S1, S2);
  k_bnfin<<<1, 256, 0, stream>>>(S1, S2, bn1_g, bn1_b, scale, shift);
  k_gemm<<<782, 256, 0, stream>>>(x, scale, shift, Bfh, Bfl, ylin, hbf);
  k_alpha<<<6250, 256, 0, stream>>>((const uint4*)hbf, (const float4*)con1_as,
                                    (const float4*)con1_ad, als, ald);
  k_hist<<<3125, 256, 0, stream>>>(dstA, counts);
  k_scanA<<<49, 1024, 0, stream>>>(counts, start, bsum);
  k_scanB<<<1, 64, 0, stream>>>(bsum, boff, start);
  k_scanC<<<49, 1024, 0, stream>>>(start, cursor, boff);
  k_scatter<<<3125, 256, 0, stream>>>(srcA, dstA, cursor, srcs);
  k_agg<<<12500, 256, 0, stream>>>((const ushort4*)hbf, (float4*)ylin, als,
                                   (const float4*)ald, start, srcs,
                                   (const float4*)lin1_b, (const float4*)con1_b);

  // ---- layer 2 ----
  hipMemsetAsync(ws + OFF_S1, 0, 512 * sizeof(float), stream);
  k_bnstats<<<1024, 256, 0, stream>>>(ylin, S1, S2);
  k_bnfin<<<1, 256, 0, stream>>>(S1, S2, bn3_g, bn3_b, scale, shift);
  k_node2<<<12500, 256, 0, stream>>>((const float4*)ylin, (const float4*)scale,
                                     (const float4*)shift, (const float4*)lin3_W,
                                     (const float4*)con3_W, con3_as, con3_ad, y3, h3,
                                     al3s, al3d);
  k_final<<<3125, 256, 0, stream>>>(start, srcs, al3s, al3d, (const float2*)h3, y3,
                                    lin3_b, con3_b, (float*)d_out);
}